// Round 4
// baseline (27906.500 us; speedup 1.0000x reference)
//
#include <hip/hip_runtime.h>
#include <stdint.h>

#define E    512
#define H    8
#define DH   64
#define BB   8
#define SS   24
#define FF   2048
#define NL   3
#define VTOK 32000
#define LBUF 25
#define ML   24
#define START_ID 1
#define NB   256   // cooperative grid blocks

// ===========================================================================
// Encoder kernels (round-3, unchanged)
// ===========================================================================
__global__ void enc_embed_kernel(const int* __restrict__ inp, const float* __restrict__ emb,
                                 float* __restrict__ x) {
  int r = blockIdx.x;
  int s = r / BB, b = r % BB;
  int tok = inp[b * SS + s];
  const float* er = emb + (size_t)tok * E;
  for (int e = threadIdx.x; e < E; e += blockDim.x) {
    int j = e >> 1;
    double dv = exp(-((double)(2 * j)) * (log(10000.0) / (double)E));
    double ang = (double)s * dv;
    double pe = (e & 1) ? cos(ang) : sin(ang);
    x[(size_t)r * E + e] = er[e] + (float)pe;
  }
}

__global__ __launch_bounds__(256) void ln_kernel(const float* __restrict__ x,
                          const float* __restrict__ g,
                          const float* __restrict__ bta, float* __restrict__ y) {
  int r = blockIdx.x;
  int t = threadIdx.x;
  const float* xr = x + (size_t)r * E;
  float a0 = xr[t], a1 = xr[t + 256];
  __shared__ float red[256];
  red[t] = a0 + a1;
  __syncthreads();
  for (int s = 128; s > 0; s >>= 1) { if (t < s) red[t] += red[t + s]; __syncthreads(); }
  float m = red[0] * (1.0f / (float)E);
  __syncthreads();
  float d0 = a0 - m, d1 = a1 - m;
  red[t] = d0 * d0 + d1 * d1;
  __syncthreads();
  for (int s = 128; s > 0; s >>= 1) { if (t < s) red[t] += red[t + s]; __syncthreads(); }
  float v = red[0] * (1.0f / (float)E);
  float rstd = 1.0f / sqrtf(v + 1e-5f);
  y[(size_t)r * E + t]       = d0 * rstd * g[t]       + bta[t];
  y[(size_t)r * E + t + 256] = d1 * rstd * g[t + 256] + bta[t + 256];
}

__global__ __launch_bounds__(256) void fgemm_kernel(
    const float* __restrict__ A, int K,
    const float* __restrict__ W, int ldw, int N,
    const float* __restrict__ bias,
    const float* __restrict__ resid,
    float* __restrict__ C, int relu) {
  __shared__ float Al[8 * 512];
  __shared__ float red[16 * 512];
  int t = threadIdx.x;
  int c0 = blockIdx.x * 64;
  int s = blockIdx.y;
  int row0 = blockIdx.z * 8;
  int kbase = s * 512;
  for (int i = t; i < 1024; i += 256) {
    int r = i >> 7, cc = i & 127;
    ((float4*)Al)[i] = *(const float4*)(A + (size_t)(row0 + r) * K + kbase + (cc << 2));
  }
  __syncthreads();
  int tc = t & 15, tk = t >> 4;
  int col = c0 + (tc << 2);
  float acc[8][4];
#pragma unroll
  for (int m = 0; m < 8; ++m) { acc[m][0] = acc[m][1] = acc[m][2] = acc[m][3] = 0.f; }
  const float4* wp = (const float4*)(W + (size_t)kbase * ldw + col);
  const size_t ld4 = (size_t)(ldw >> 2);
#pragma unroll 8
  for (int i = 0; i < 32; ++i) {
    int k = tk + (i << 4);
    float4 wv = wp[(size_t)k * ld4];
#pragma unroll
    for (int m = 0; m < 8; ++m) {
      float a = Al[m * 512 + k];
      acc[m][0] += a * wv.x; acc[m][1] += a * wv.y;
      acc[m][2] += a * wv.z; acc[m][3] += a * wv.w;
    }
  }
#pragma unroll
  for (int m = 0; m < 8; ++m) {
    float4* rr = (float4*)&red[tk * 512 + m * 64 + (tc << 2)];
    *rr = make_float4(acc[m][0], acc[m][1], acc[m][2], acc[m][3]);
  }
  __syncthreads();
  float out2[2];
#pragma unroll
  for (int j = 0; j < 2; ++j) {
    int o = t + j * 256;
    float v = 0.f;
#pragma unroll
    for (int sl = 0; sl < 16; ++sl) v += red[sl * 512 + o];
    out2[j] = v;
  }
  int S = gridDim.y;
  if (S > 1) {
    int M = gridDim.z * 8;
#pragma unroll
    for (int j = 0; j < 2; ++j) {
      int o = t + j * 256; int m = o >> 6, cc = o & 63;
      C[((size_t)s * M + row0 + m) * N + c0 + cc] = out2[j];
    }
  } else {
#pragma unroll
    for (int j = 0; j < 2; ++j) {
      int o = t + j * 256; int m = o >> 6, cc = o & 63;
      int col2 = c0 + cc;
      float v = out2[j] + bias[col2];
      if (resid) v += resid[(size_t)(row0 + m) * N + col2];
      if (relu) v = fmaxf(v, 0.0f);
      C[(size_t)(row0 + m) * N + col2] = v;
    }
  }
}

__global__ __launch_bounds__(256) void reduce_br_kernel(const float* __restrict__ part, int S, int M,
                                 const float* __restrict__ bias,
                                 const float* __restrict__ resid,
                                 float* __restrict__ outp) {
  int r = blockIdx.x, t = threadIdx.x;
#pragma unroll
  for (int j = 0; j < 2; ++j) {
    int c = t + j * 256;
    float v = bias[c] + resid[(size_t)r * E + c];
    for (int s = 0; s < S; ++s) v += part[((size_t)s * M + r) * E + c];
    outp[(size_t)r * E + c] = v;
  }
}

__global__ void enc_attn_kernel(const float* __restrict__ qkv, float* __restrict__ o) {
  int b = blockIdx.x >> 3, h = blockIdx.x & 7;
  __shared__ float qs[SS * DH], ks[SS * DH], vs[SS * DH];
  __shared__ float sc[SS][SS];
  int t = threadIdx.x;
  for (int idx = t; idx < SS * DH; idx += 256) {
    int srow = idx / DH, d = idx - srow * DH;
    size_t base = ((size_t)(srow * BB + b)) * (3 * E) + h * DH + d;
    qs[idx] = qkv[base];
    ks[idx] = qkv[base + E];
    vs[idx] = qkv[base + 2 * E];
  }
  __syncthreads();
  for (int p = t; p < SS * SS; p += 256) {
    int qi = p / SS, kj = p - qi * SS;
    float a = 0.f;
    for (int d = 0; d < DH; ++d) a += qs[qi * DH + d] * ks[kj * DH + d];
    sc[qi][kj] = a * 0.125f;
  }
  __syncthreads();
  if (t < SS) {
    float mx = -1e30f;
    for (int j = 0; j < SS; ++j) mx = fmaxf(mx, sc[t][j]);
    float sm = 0.f;
    for (int j = 0; j < SS; ++j) { float ev = expf(sc[t][j] - mx); sc[t][j] = ev; sm += ev; }
    float inv = 1.0f / sm;
    for (int j = 0; j < SS; ++j) sc[t][j] *= inv;
  }
  __syncthreads();
  for (int p = t; p < SS * DH; p += 256) {
    int qi = p / DH, d = p - qi * DH;
    float a = 0.f;
    for (int j = 0; j < SS; ++j) a += sc[qi][j] * vs[j * DH + d];
    o[((size_t)(qi * BB + b)) * E + h * DH + d] = a;
  }
}

// ===========================================================================
// Cooperative decode mega-kernel
// ===========================================================================
struct DP {
  const float *emb;
  const float *saw, *sab, *saow, *saob;
  const float *caw, *cab, *caow, *caob;
  const float *l1g, *l1b, *l2g, *l2b, *l3g, *l3b;
  const float *f1w, *f1b, *f2w, *f2b;
  const float *ng, *nb, *vw, *vb;
  const float *memk, *memv;
  float *cacheK, *cacheV;
  float *pqkv, *part, *pq, *pm, *pf;
  float *y0, *y1, *y2;
  int *tokens;
  unsigned long long *amax;
  unsigned *bar;
  float *out;
};

__device__ __forceinline__ void gbar(unsigned* bar) {
  __syncthreads();
  if (threadIdx.x == 0) {
    __threadfence();
    unsigned g = __hip_atomic_load(&bar[1], __ATOMIC_RELAXED, __HIP_MEMORY_SCOPE_AGENT);
    unsigned a = __hip_atomic_fetch_add(&bar[0], 1u, __ATOMIC_ACQ_REL, __HIP_MEMORY_SCOPE_AGENT);
    if (a == gridDim.x - 1) {
      __hip_atomic_store(&bar[0], 0u, __ATOMIC_RELAXED, __HIP_MEMORY_SCOPE_AGENT);
      __hip_atomic_store(&bar[1], g + 1u, __ATOMIC_RELEASE, __HIP_MEMORY_SCOPE_AGENT);
    } else {
      while (__hip_atomic_load(&bar[1], __ATOMIC_ACQUIRE, __HIP_MEMORY_SCOPE_AGENT) == g)
        __builtin_amdgcn_s_sleep(1);
    }
    __threadfence();
  }
  __syncthreads();
}

// raw[8][512] = resid + bias + sum_s parts[s][m][512]  -> sA
__device__ __forceinline__ void build_raw(const float* __restrict__ resid,
                                          const float* __restrict__ bias,
                                          const float* __restrict__ parts, int nslices,
                                          float* sA) {
  int t = threadIdx.x;
  for (int o = t; o < 4096; o += 256) {
    int m = o >> 9, c = o & 511;
    float v = resid[m * 512 + c] + bias[c];
    for (int s = 0; s < nslices; ++s) v += parts[(s * 8 + m) * 512 + c];
    sA[o] = v;
  }
  __syncthreads();
}

// in-place rowwise LayerNorm of sA[8][512]
__device__ __forceinline__ void row_ln(float* sA, const float* __restrict__ g,
                                       const float* __restrict__ bv, float* stat) {
  int t = threadIdx.x;
  int r = t >> 5, l = t & 31;
  float s = 0.f;
  for (int j = l; j < 512; j += 32) s += sA[r * 512 + j];
  for (int off = 16; off; off >>= 1) s += __shfl_down(s, off, 32);
  if (l == 0) stat[r] = s * (1.f / 512.f);
  __syncthreads();
  float m = stat[r];
  float s2 = 0.f;
  for (int j = l; j < 512; j += 32) { float d = sA[r * 512 + j] - m; s2 += d * d; }
  for (int off = 16; off; off >>= 1) s2 += __shfl_down(s2, off, 32);
  if (l == 0) stat[8 + r] = s2 * (1.f / 512.f);
  __syncthreads();
  for (int o = t; o < 4096; o += 256) {
    int rr = o >> 9, c = o & 511;
    float rstd = rsqrtf(stat[8 + rr] + 1e-5f);
    sA[o] = (sA[o] - stat[rr]) * rstd * g[c] + bv[c];
  }
  __syncthreads();
}

// 8-row x 64-col tile GEMM over k in [0,KW); A slice at sAb[m*rstride + la0 + k]
template <int KW>
__device__ __forceinline__ void tile_gemm(const float* __restrict__ sAb, int rstride, int la0,
                                          const float* __restrict__ W, int ldw, int wk0, int col0,
                                          float* sRed, float out2[2]) {
  int t = threadIdx.x;
  int tq = t & 15, tk = t >> 4;
  float acc[8][4];
#pragma unroll
  for (int m = 0; m < 8; ++m) { acc[m][0] = acc[m][1] = acc[m][2] = acc[m][3] = 0.f; }
  const float* wbase = W + (size_t)wk0 * ldw + col0 + (tq << 2);
#pragma unroll 8
  for (int i = 0; i < KW / 16; ++i) {
    int k = tk + (i << 4);
    float4 wv = *(const float4*)(wbase + (size_t)k * ldw);
#pragma unroll
    for (int m = 0; m < 8; ++m) {
      float a = sAb[m * rstride + la0 + k];
      acc[m][0] += a * wv.x; acc[m][1] += a * wv.y;
      acc[m][2] += a * wv.z; acc[m][3] += a * wv.w;
    }
  }
  __syncthreads();
#pragma unroll
  for (int m = 0; m < 8; ++m)
    *(float4*)&sRed[tk * 512 + m * 64 + (tq << 2)] =
        make_float4(acc[m][0], acc[m][1], acc[m][2], acc[m][3]);
  __syncthreads();
#pragma unroll
  for (int j = 0; j < 2; ++j) {
    int o = t + (j << 8);
    float v = 0.f;
#pragma unroll
    for (int sl = 0; sl < 16; ++sl) v += sRed[sl * 512 + o];
    out2[j] = v;
  }
}

__global__ __launch_bounds__(256) void dec_coop(DP p) {
  __shared__ float sA[4096];    // 16 KB: activation rows / A tiles
  __shared__ float sRed[8192];  // 32 KB: gemm reduce / attn scratch / argmax keys
  __shared__ float sStat[16];
  int bid = blockIdx.x, t = threadIdx.x;

  for (int i = 0; i < ML; ++i) {
    for (int l = 0; l < NL; ++l) {
      const float* saw  = p.saw  + (size_t)l * E * 3 * E;
      const float* sab  = p.sab  + (size_t)l * 3 * E;
      const float* saow = p.saow + (size_t)l * E * E;
      const float* saob = p.saob + (size_t)l * E;
      const float* caw  = p.caw  + (size_t)l * E * 3 * E;
      const float* cab  = p.cab  + (size_t)l * 3 * E;
      const float* caow = p.caow + (size_t)l * E * E;
      const float* caob = p.caob + (size_t)l * E;
      const float* f1w  = p.f1w + (size_t)l * E * FF;
      const float* f1b  = p.f1b + (size_t)l * FF;
      const float* f2w  = p.f2w + (size_t)l * FF * E;
      const float* f2b  = p.f2b + (size_t)l * E;
      float* Kc = p.cacheK + (size_t)l * LBUF * BB * E;
      float* Vc = p.cacheV + (size_t)l * LBUF * BB * E;
      const float* mk = p.memk + (size_t)l * SS * BB * E;
      const float* mv = p.memv + (size_t)l * SS * BB * E;

      // ---- P1: layer input + qkv partial GEMM (192 blocks) ----
      if (bid < 192) {
        if (l == 0) {
          for (int o = t; o < 4096; o += 256) {
            int m = o >> 9, c = o & 511;
            int tok = p.tokens[i * BB + m];
            sA[o] = p.emb[(size_t)tok * E + c];
          }
          __syncthreads();
        } else {
          // y0 = LN3(y2 + f2b(prev) + sum pf) of PREVIOUS layer
          const float* pf2b = p.f2b + (size_t)(l - 1) * E;
          build_raw(p.y2, pf2b, p.pf, 8, sA);
          row_ln(sA, p.l3g + (l - 1) * E, p.l3b + (l - 1) * E, sStat);
        }
        if (bid < 8) {
          for (int c = t; c < 512; c += 256) p.y0[bid * 512 + c] = sA[bid * 512 + c];
        }
        int cc = bid >> 3, ks = bid & 7;
        float out2[2];
        tile_gemm<64>(sA, 512, ks * 64, saw, 3 * E, ks * 64, cc * 64, sRed, out2);
#pragma unroll
        for (int j = 0; j < 2; ++j) {
          int o = t + (j << 8); int m = o >> 6, c = o & 63;
          p.pqkv[(size_t)(ks * 8 + m) * (3 * E) + cc * 64 + c] = out2[j];
        }
      }
      gbar(p.bar);

      // ---- P2: self-attn + out-proj partials (64 blocks = (b,h)) ----
      if (bid < 64) {
        int b = bid >> 3, h = bid & 7;
        float* sQ = sRed; float* sK = sRed + 64; float* sV = sRed + 128;
        float* sO = sRed + 192; float* sSc = sRed + 256;
        if (t < 192) {
          int which = t >> 6, d = t & 63;
          int col = which * E + h * DH + d;
          float v = sab[col];
          for (int ks = 0; ks < 8; ++ks) v += p.pqkv[(size_t)(ks * 8 + b) * (3 * E) + col];
          sRed[t] = v;  // q|k|v packed
        }
        __syncthreads();
        if (t < 128) {  // write KV cache at pos i
          int which = t >> 6, d = t & 63;
          float v = sRed[64 + t];
          float* dst = (which == 0 ? Kc : Vc) + ((size_t)i * BB + b) * E + h * DH + d;
          *dst = v;
        }
        int L = i + 1;
        if (t < L) {
          const float* kr = (t == i) ? sK : (Kc + ((size_t)t * BB + b) * E + h * DH);
          float s = 0.f;
#pragma unroll 8
          for (int d = 0; d < DH; ++d) s += sQ[d] * kr[d];
          sSc[t] = s * 0.125f;
        }
        __syncthreads();
        if (t == 0) {
          float mx = -1e30f;
          for (int j = 0; j < L; ++j) mx = fmaxf(mx, sSc[j]);
          float sm = 0.f;
          for (int j = 0; j < L; ++j) { float ev = expf(sSc[j] - mx); sSc[j] = ev; sm += ev; }
          float inv = 1.0f / sm;
          for (int j = 0; j < L; ++j) sSc[j] *= inv;
        }
        __syncthreads();
        if (t < DH) {
          float a = 0.f;
          for (int j = 0; j < L; ++j) {
            float vv = (j == i) ? sV[t] : Vc[((size_t)j * BB + b) * E + h * DH + t];
            a += sSc[j] * vv;
          }
          sO[t] = a;
        }
        __syncthreads();
#pragma unroll
        for (int j = 0; j < 2; ++j) {
          int c = t + (j << 8);
          float acc = 0.f;
          const float* w = saow + (size_t)(h * DH) * E + c;
#pragma unroll 8
          for (int kk = 0; kk < DH; ++kk) acc += sO[kk] * w[(size_t)kk * E];
          p.part[(size_t)(h * 8 + b) * E + c] = acc;
        }
      }
      gbar(p.bar);

      // ---- P4: y1 = LN1(y0 + saob + sum part); q GEMM partials (64 blocks) ----
      if (bid < 64) {
        build_raw(p.y0, saob, p.part, 8, sA);
        row_ln(sA, p.l1g + l * E, p.l1b + l * E, sStat);
        if (bid < 8) {
          for (int c = t; c < 512; c += 256) p.y1[bid * 512 + c] = sA[bid * 512 + c];
        }
        int cc = bid >> 3, ks = bid & 7;
        float out2[2];
        tile_gemm<64>(sA, 512, ks * 64, caw, 3 * E, ks * 64, cc * 64, sRed, out2);
#pragma unroll
        for (int j = 0; j < 2; ++j) {
          int o = t + (j << 8); int m = o >> 6, c = o & 63;
          p.pq[(size_t)(ks * 8 + m) * E + cc * 64 + c] = out2[j];
        }
      }
      gbar(p.bar);

      // ---- P5: cross-attn + out-proj partials (64 blocks) ----
      if (bid < 64) {
        int b = bid >> 3, h = bid & 7;
        float* sQ = sRed; float* sO = sRed + 64; float* sSc = sRed + 128;
        if (t < 64) {
          float v = cab[h * DH + t];
          for (int ks = 0; ks < 8; ++ks) v += p.pq[(size_t)(ks * 8 + b) * E + h * DH + t];
          sQ[t] = v;
        }
        __syncthreads();
        if (t < SS) {
          const float* kr = mk + ((size_t)t * BB + b) * E + h * DH;
          float s = 0.f;
#pragma unroll 8
          for (int d = 0; d < DH; ++d) s += sQ[d] * kr[d];
          sSc[t] = s * 0.125f;
        }
        __syncthreads();
        if (t == 0) {
          float mx = -1e30f;
          for (int j = 0; j < SS; ++j) mx = fmaxf(mx, sSc[j]);
          float sm = 0.f;
          for (int j = 0; j < SS; ++j) { float ev = expf(sSc[j] - mx); sSc[j] = ev; sm += ev; }
          float inv = 1.0f / sm;
          for (int j = 0; j < SS; ++j) sSc[j] *= inv;
        }
        __syncthreads();
        if (t < DH) {
          float a = 0.f;
          for (int j = 0; j < SS; ++j) a += sSc[j] * mv[((size_t)j * BB + b) * E + h * DH + t];
          sO[t] = a;
        }
        __syncthreads();
#pragma unroll
        for (int j = 0; j < 2; ++j) {
          int c = t + (j << 8);
          float acc = 0.f;
          const float* w = caow + (size_t)(h * DH) * E + c;
#pragma unroll 8
          for (int kk = 0; kk < DH; ++kk) acc += sO[kk] * w[(size_t)kk * E];
          p.part[(size_t)(h * 8 + b) * E + c] = acc;
        }
      }
      gbar(p.bar);

      // ---- P7: y2 = LN2(y1 + caob + sum part); FFN1 partials (64 blocks) ----
      if (bid < 64) {
        build_raw(p.y1, caob, p.part, 8, sA);
        row_ln(sA, p.l2g + l * E, p.l2b + l * E, sStat);
        if (bid < 8) {
          for (int c = t; c < 512; c += 256) p.y2[bid * 512 + c] = sA[bid * 512 + c];
        }
        int cc = bid >> 1, ks = bid & 1;
        float out2[2];
        tile_gemm<256>(sA, 512, ks * 256, f1w, FF, ks * 256, cc * 64, sRed, out2);
#pragma unroll
        for (int j = 0; j < 2; ++j) {
          int o = t + (j << 8); int m = o >> 6, c = o & 63;
          p.pm[(size_t)(ks * 8 + m) * FF + cc * 64 + c] = out2[j];
        }
      }
      gbar(p.bar);

      // ---- P8: mid=relu(pm0+pm1+b1); FFN2 partials (64 blocks) ----
      if (bid < 64) {
        int cc = bid >> 3, ks = bid & 7;
        for (int o = t; o < 2048; o += 256) {
          int m = o >> 8, j = o & 255;
          int k = ks * 256 + j;
          float v = f1b[k] + p.pm[(size_t)m * FF + k] + p.pm[(size_t)(8 + m) * FF + k];
          sA[m * 256 + j] = fmaxf(v, 0.0f);
        }
        __syncthreads();
        float out2[2];
        tile_gemm<256>(sA, 256, 0, f2w, E, ks * 256, cc * 64, sRed, out2);
#pragma unroll
        for (int j = 0; j < 2; ++j) {
          int o = t + (j << 8); int m = o >> 6, c = o & 63;
          p.pf[(size_t)(ks * 8 + m) * E + cc * 64 + c] = out2[j];
        }
      }
      gbar(p.bar);
    }

    // ---- Vocab: yf = LNf(LN3(y2 + f2b + sum pf)); big GEMM + argmax ----
    {
      const float* f2b2 = p.f2b + (size_t)2 * E;
      build_raw(p.y2, f2b2, p.pf, 8, sA);
      row_ln(sA, p.l3g + 2 * E, p.l3b + 2 * E, sStat);
      row_ln(sA, p.ng, p.nb, sStat);
      float* dist_i = p.out + 192 + (size_t)i * (BB * VTOK);
      for (int ch = bid; ch < 500; ch += NB) {
        int col0 = ch * 64;
        float out2[2];
        tile_gemm<512>(sA, 512, 0, p.vw, VTOK, 0, col0, sRed, out2);
        unsigned long long* keys = (unsigned long long*)sRed;
#pragma unroll
        for (int j = 0; j < 2; ++j) {
          int o = t + (j << 8); int m = o >> 6, c = o & 63;
          int col = col0 + c;
          float v = out2[j] + p.vb[col];
          dist_i[(size_t)m * VTOK + col] = v;
          unsigned int fb = __float_as_uint(v);
          fb = (fb & 0x80000000u) ? ~fb : (fb | 0x80000000u);
          keys[o] = ((unsigned long long)fb << 32) |
                    (unsigned long long)(0xFFFFFFFFu - (unsigned)col);
        }
        __syncthreads();
        if (t < 8) {
          unsigned long long best = 0ull;
          for (int c = 0; c < 64; ++c) {
            unsigned long long k = keys[t * 64 + c];
            if (k > best) best = k;
          }
          atomicMax(&p.amax[t], best);
        }
        __syncthreads();
      }
    }
    gbar(p.bar);

    // ---- Token finalize ----
    if (bid == 0 && t < BB) {
      unsigned long long v = p.amax[t];
      int idx = (int)(0xFFFFFFFFu - (unsigned int)(v & 0xFFFFFFFFull));
      p.tokens[(i + 1) * BB + t] = idx;
      p.out[i * BB + t] = (float)idx;
      p.amax[t] = 0ull;
    }
    gbar(p.bar);
  }
}

__global__ void dec_init_kernel(int* __restrict__ tokens, unsigned long long* __restrict__ amax,
                                unsigned* __restrict__ bar) {
  int t = threadIdx.x;
  if (t < BB) { tokens[t] = START_ID; amax[t] = 0ull; }
  if (t < 4) bar[t] = 0u;
}

// ===========================================================================
extern "C" void kernel_launch(void* const* d_in, const int* in_sizes, int n_in,
                              void* d_out, int out_size, void* d_ws, size_t ws_size,
                              hipStream_t stream) {
  (void)in_sizes; (void)n_in; (void)out_size; (void)ws_size;
  const int*   inp   = (const int*)d_in[0];
  const float* emb   = (const float*)d_in[1];
  const float* e_aw  = (const float*)d_in[2];
  const float* e_ab  = (const float*)d_in[3];
  const float* e_aow = (const float*)d_in[4];
  const float* e_aob = (const float*)d_in[5];
  const float* e_l1g = (const float*)d_in[6];
  const float* e_l1b = (const float*)d_in[7];
  const float* e_l2g = (const float*)d_in[8];
  const float* e_l2b = (const float*)d_in[9];
  const float* e_f1w = (const float*)d_in[10];
  const float* e_f1b = (const float*)d_in[11];
  const float* e_f2w = (const float*)d_in[12];
  const float* e_f2b = (const float*)d_in[13];
  const float* e_ng  = (const float*)d_in[14];
  const float* e_nb  = (const float*)d_in[15];
  const float* d_saw = (const float*)d_in[16];
  const float* d_sab = (const float*)d_in[17];
  const float* d_saow= (const float*)d_in[18];
  const float* d_saob= (const float*)d_in[19];
  const float* d_caw = (const float*)d_in[20];
  const float* d_cab = (const float*)d_in[21];
  const float* d_caow= (const float*)d_in[22];
  const float* d_caob= (const float*)d_in[23];
  const float* d_l1g = (const float*)d_in[24];
  const float* d_l1b = (const float*)d_in[25];
  const float* d_l2g = (const float*)d_in[26];
  const float* d_l2b = (const float*)d_in[27];
  const float* d_l3g = (const float*)d_in[28];
  const float* d_l3b = (const float*)d_in[29];
  const float* d_f1w = (const float*)d_in[30];
  const float* d_f1b = (const float*)d_in[31];
  const float* d_f2w = (const float*)d_in[32];
  const float* d_f2b = (const float*)d_in[33];
  const float* d_ng  = (const float*)d_in[34];
  const float* d_nb  = (const float*)d_in[35];
  const float* voc_w = (const float*)d_in[36];
  const float* voc_b = (const float*)d_in[37];
  float* out = (float*)d_out;

  // workspace carve-up (floats)
  float* p = (float*)d_ws;
  auto alloc = [&](size_t n) { float* r = p; p += n; return r; };
  float* enc_x   = alloc(192 * 512);
  float* enc_tmp = alloc(192 * 2048);
  float* enc_ao  = alloc(192 * 512);
  float* enc_raw = alloc(192 * 512);
  float* memry   = alloc(192 * 512);
  float* mem_k   = alloc(3 * 192 * 512);
  float* mem_v   = alloc(3 * 192 * 512);
  float* partE   = alloc(4 * 192 * 512);
  float* pqkv    = alloc(8 * 8 * 1536);
  float* partb   = alloc(8 * 8 * 512);
  float* pq      = alloc(8 * 8 * 512);
  float* pmb     = alloc(2 * 8 * 2048);
  float* pfb     = alloc(8 * 8 * 512);
  float* y0      = alloc(8 * 512);
  float* y1      = alloc(8 * 512);
  float* y2      = alloc(8 * 512);
  float* cacheK  = alloc(3 * LBUF * 8 * 512);
  float* cacheV  = alloc(3 * LBUF * 8 * 512);
  int* tokens    = (int*)alloc(LBUF * 8);
  unsigned long long* amax = (unsigned long long*)alloc(16);
  unsigned* bar  = (unsigned*)alloc(16);

  // ---------------- encoder ----------------
  enc_embed_kernel<<<dim3(192), dim3(256), 0, stream>>>(inp, emb, enc_x);
  for (int l = 0; l < NL; ++l) {
    const float* w  = e_aw  + (size_t)l * E * 3 * E;
    const float* bq = e_ab  + (size_t)l * 3 * E;
    fgemm_kernel<<<dim3(24, 1, 24), dim3(256), 0, stream>>>(
        enc_x, E, w, 3 * E, 3 * E, bq, nullptr, enc_tmp, 0);
    enc_attn_kernel<<<dim3(64), dim3(256), 0, stream>>>(enc_tmp, enc_ao);
    fgemm_kernel<<<dim3(8, 1, 24), dim3(256), 0, stream>>>(
        enc_ao, E, e_aow + (size_t)l * E * E, E, E, e_aob + (size_t)l * E,
        enc_x, enc_raw, 0);
    ln_kernel<<<dim3(192), dim3(256), 0, stream>>>(enc_raw, e_l1g + l * E, e_l1b + l * E, enc_x);
    fgemm_kernel<<<dim3(32, 1, 24), dim3(256), 0, stream>>>(
        enc_x, E, e_f1w + (size_t)l * E * FF, FF, FF, e_f1b + (size_t)l * FF,
        nullptr, enc_tmp, 1);
    fgemm_kernel<<<dim3(8, 4, 24), dim3(256), 0, stream>>>(
        enc_tmp, FF, e_f2w + (size_t)l * FF * E, E, E, nullptr,
        nullptr, partE, 0);
    reduce_br_kernel<<<dim3(192), dim3(256), 0, stream>>>(
        partE, 4, 192, e_f2b + (size_t)l * E, enc_x, enc_raw);
    ln_kernel<<<dim3(192), dim3(256), 0, stream>>>(enc_raw, e_l2g + l * E, e_l2b + l * E, enc_x);
  }
  ln_kernel<<<dim3(192), dim3(256), 0, stream>>>(enc_x, e_ng, e_nb, memry);

  for (int l = 0; l < NL; ++l) {
    const float* w  = d_caw + (size_t)l * E * 3 * E;
    const float* bq = d_cab + (size_t)l * 3 * E;
    fgemm_kernel<<<dim3(8, 1, 24), dim3(256), 0, stream>>>(
        memry, E, w + E, 3 * E, E, bq + E, nullptr,
        mem_k + (size_t)l * 192 * 512, 0);
    fgemm_kernel<<<dim3(8, 1, 24), dim3(256), 0, stream>>>(
        memry, E, w + 2 * E, 3 * E, E, bq + 2 * E, nullptr,
        mem_v + (size_t)l * 192 * 512, 0);
  }

  // ---------------- cooperative decode ----------------
  dec_init_kernel<<<dim3(1), dim3(64), 0, stream>>>(tokens, amax, bar);

  DP dp;
  dp.emb = emb;
  dp.saw = d_saw; dp.sab = d_sab; dp.saow = d_saow; dp.saob = d_saob;
  dp.caw = d_caw; dp.cab = d_cab; dp.caow = d_caow; dp.caob = d_caob;
  dp.l1g = d_l1g; dp.l1b = d_l1b; dp.l2g = d_l2g; dp.l2b = d_l2b;
  dp.l3g = d_l3g; dp.l3b = d_l3b;
  dp.f1w = d_f1w; dp.f1b = d_f1b; dp.f2w = d_f2w; dp.f2b = d_f2b;
  dp.ng = d_ng; dp.nb = d_nb; dp.vw = voc_w; dp.vb = voc_b;
  dp.memk = mem_k; dp.memv = mem_v;
  dp.cacheK = cacheK; dp.cacheV = cacheV;
  dp.pqkv = pqkv; dp.part = partb; dp.pq = pq; dp.pm = pmb; dp.pf = pfb;
  dp.y0 = y0; dp.y1 = y1; dp.y2 = y2;
  dp.tokens = tokens; dp.amax = amax; dp.bar = bar;
  dp.out = out;

  void* kargs[] = { &dp };
  hipLaunchCooperativeKernel((const void*)dec_coop, dim3(NB), dim3(256), kargs, 0, stream);
}